// Round 1
// baseline (499.423 us; speedup 1.0000x reference)
//
#include <hip/hip_runtime.h>

#define B_ 16
#define F_ 128
#define N_ 256
#define T_ 64
#define C_ 64
#define NEG_INF_ -9000000000000000.0f
#define ALPHA_ 0.2f

__device__ __forceinline__ unsigned short f2bf(float x){
  unsigned int u = __float_as_uint(x);
  unsigned int r = u + 0x7FFFu + ((u >> 16) & 1u);   // RNE
  return (unsigned short)(r >> 16);
}

// ---------------- Kernel A: u1[b][f] = sum_c W[b][f][c]*a1[b][c]; u2 with a2
__global__ void k_u(const float* __restrict__ W, const float* __restrict__ a,
                    float* __restrict__ u){
  int b = blockIdx.x, f = threadIdx.x;            // grid(B), block(F)
  const float* Wb = W + (b*F_ + f)*C_;
  const float* ab = a + b*2*C_;
  float s1 = 0.f, s2 = 0.f;
#pragma unroll 8
  for (int c = 0; c < C_; ++c){
    float w = Wb[c];
    s1 = fmaf(w, ab[c], s1);
    s2 = fmaf(w, ab[C_ + c], s2);
  }
  u[b*F_ + f] = s1;
  u[B_*F_ + b*F_ + f] = s2;
}

// ---------------- Kernel B: per (b,n): Wh_t[b][t][n][c] (bf16), and f,g (f32)
__global__ __launch_bounds__(256) void k_wh(const float* __restrict__ h,
    const float* __restrict__ W, const float* __restrict__ u,
    unsigned short* __restrict__ wht, float* __restrict__ fvec,
    float* __restrict__ gvec){
  __shared__ float hs[F_][T_];   // 32KB  (f x t)
  __shared__ float Ws[F_][C_];   // 32KB  (f x c)
  int bid = blockIdx.x;
  int b = bid >> 8, n = bid & 255;
  int tid = threadIdx.x;
  const float* hb = h + (size_t)b*F_*N_*T_ + n*T_;
#pragma unroll
  for (int i = 0; i < 8; ++i){
    int chunk = tid + i*256;                 // 2048 float4 chunks
    int f = chunk >> 4, tc = (chunk & 15)*4;
    *(float4*)&hs[f][tc] = *(const float4*)(hb + (size_t)f*(N_*T_) + tc);
  }
  const float* Wb = W + b*(F_*C_);
#pragma unroll
  for (int i = 0; i < 8; ++i){
    int chunk = tid + i*256;
    *(float4*)(&Ws[0][0] + chunk*4) = *(const float4*)(Wb + chunk*4);
  }
  __syncthreads();

  int c0 = (tid & 15)*4, t0 = (tid >> 4)*4;
  float acc[4][4] = {};
#pragma unroll 2
  for (int f = 0; f < F_; ++f){
    float wv[4], hv[4];
    *(float4*)wv = *(const float4*)&Ws[f][c0];
    *(float4*)hv = *(const float4*)&hs[f][t0];
#pragma unroll
    for (int i = 0; i < 4; ++i)
#pragma unroll
      for (int j = 0; j < 4; ++j)
        acc[i][j] = fmaf(wv[i], hv[j], acc[i][j]);
  }

  // f,g in full f32 (precision-critical for the sharp softmax logits)
  if (tid < T_){
    const float* u1 = u + b*F_;
    const float* u2 = u + B_*F_ + b*F_;
    float sf = 0.f, sg = 0.f;
#pragma unroll 4
    for (int f = 0; f < F_; ++f){
      float hv = hs[f][tid];
      sf = fmaf(hv, u1[f], sf);
      sg = fmaf(hv, u2[f], sg);
    }
    fvec[(b*N_ + n)*T_ + tid] = sf;
    gvec[(b*N_ + n)*T_ + tid] = sg;
  }

  // store Wh_t[b][t][n][c] as bf16, coalesced over c
#pragma unroll
  for (int j = 0; j < 4; ++j){
    unsigned int p0 = ((unsigned int)f2bf(acc[1][j]) << 16) | f2bf(acc[0][j]);
    unsigned int p1 = ((unsigned int)f2bf(acc[3][j]) << 16) | f2bf(acc[2][j]);
    size_t idx = ((size_t)(b*T_ + t0 + j)*N_ + n)*C_ + c0;
    *(uint2*)(wht + idx) = make_uint2(p0, p1);
  }
}

// ---------------- Kernel C: per (b,t): softmax over m + PV; writes (b,t,n,c) into d_out
__global__ __launch_bounds__(256) void k_attn(const unsigned short* __restrict__ wht,
    const int* __restrict__ adj, const float* __restrict__ fvec,
    const float* __restrict__ gvec, float* __restrict__ outt){
  __shared__ unsigned short Whs[N_][C_];       // 32KB bf16  (m x c)
  __shared__ unsigned short attn_s[4][8][N_];  // 16KB bf16  per-wave scratch
  __shared__ float f_s[N_], g_s[N_];
  int bid = blockIdx.x;
  int b = bid >> 6, t = bid & 63;
  int tid = threadIdx.x, w = tid >> 6, lane = tid & 63;

  f_s[tid] = fvec[(b*N_ + tid)*T_ + t];
  g_s[tid] = gvec[(b*N_ + tid)*T_ + t];
  const uint4* src = (const uint4*)(wht + (size_t)(b*T_ + t)*(N_*C_));
  uint4* dst = (uint4*)&Whs[0][0];
#pragma unroll
  for (int i = 0; i < 8; ++i) dst[tid + i*256] = src[tid + i*256];
  __syncthreads();

  const int* adjb = adj + (size_t)b*N_*N_;
  int mi = lane & 7, cg = lane >> 3;

  for (int g8 = 0; g8 < 8; ++g8){
    int n0 = g8*32 + w*8;
    // ---- phase 1: masked leaky-relu logits -> softmax weights (wave-parallel over m)
#pragma unroll
    for (int np = 0; np < 8; ++np){
      int n = n0 + np;
      float fv = f_s[n];
      int4 aj = *(const int4*)(adjb + n*N_ + lane*4);
      float4 gv = *(const float4*)&g_s[lane*4];
      float e0 = fv + gv.x; e0 = e0 > 0.f ? e0 : ALPHA_*e0; e0 = aj.x > 0 ? e0 : NEG_INF_;
      float e1 = fv + gv.y; e1 = e1 > 0.f ? e1 : ALPHA_*e1; e1 = aj.y > 0 ? e1 : NEG_INF_;
      float e2 = fv + gv.z; e2 = e2 > 0.f ? e2 : ALPHA_*e2; e2 = aj.z > 0 ? e2 : NEG_INF_;
      float e3 = fv + gv.w; e3 = e3 > 0.f ? e3 : ALPHA_*e3; e3 = aj.w > 0 ? e3 : NEG_INF_;
      float mx = fmaxf(fmaxf(e0,e1), fmaxf(e2,e3));
#pragma unroll
      for (int s = 1; s < 64; s <<= 1) mx = fmaxf(mx, __shfl_xor(mx, s));
      float w0 = __expf(e0-mx), w1 = __expf(e1-mx), w2 = __expf(e2-mx), w3 = __expf(e3-mx);
      float sm = (w0+w1)+(w2+w3);
#pragma unroll
      for (int s = 1; s < 64; s <<= 1) sm += __shfl_xor(sm, s);
      float inv = 1.f / sm;
      unsigned int q0 = ((unsigned int)f2bf(w1*inv) << 16) | f2bf(w0*inv);
      unsigned int q1 = ((unsigned int)f2bf(w3*inv) << 16) | f2bf(w2*inv);
      *(uint2*)&attn_s[w][np][lane*4] = make_uint2(q0, q1);
    }
    // ---- phase 2: h_prime[c,n] = sum_m attn[n][m] * Whs[m][c]; mi-split over m
    float acc[8][8];
#pragma unroll
    for (int i = 0; i < 8; ++i)
#pragma unroll
      for (int k = 0; k < 8; ++k) acc[i][k] = 0.f;

    for (int mq = 0; mq < 32; ++mq){
      int m = mq*8 + mi;
      uint4 uu = *(const uint4*)&Whs[m][cg*8];
      float wh[8];
      wh[0]=__uint_as_float(uu.x<<16); wh[1]=__uint_as_float(uu.x&0xFFFF0000u);
      wh[2]=__uint_as_float(uu.y<<16); wh[3]=__uint_as_float(uu.y&0xFFFF0000u);
      wh[4]=__uint_as_float(uu.z<<16); wh[5]=__uint_as_float(uu.z&0xFFFF0000u);
      wh[6]=__uint_as_float(uu.w<<16); wh[7]=__uint_as_float(uu.w&0xFFFF0000u);
#pragma unroll
      for (int np = 0; np < 8; ++np){
        float av = __uint_as_float(((unsigned int)attn_s[w][np][m]) << 16);
#pragma unroll
        for (int k = 0; k < 8; ++k) acc[np][k] = fmaf(av, wh[k], acc[np][k]);
      }
    }
    // butterfly-reduce partial sums across the 8 mi lanes
#pragma unroll
    for (int np = 0; np < 8; ++np){
#pragma unroll
      for (int k = 0; k < 8; ++k){
        float v = acc[np][k];
        v += __shfl_xor(v, 1);
        v += __shfl_xor(v, 2);
        v += __shfl_xor(v, 4);
        acc[np][k] = v;
      }
    }
    // lane stores c == lane: select k == mi via cndmask tree, apply ELU
#pragma unroll
    for (int np = 0; np < 8; ++np){
      float v0 = (mi & 1) ? acc[np][1] : acc[np][0];
      float v1 = (mi & 1) ? acc[np][3] : acc[np][2];
      float v2 = (mi & 1) ? acc[np][5] : acc[np][4];
      float v3 = (mi & 1) ? acc[np][7] : acc[np][6];
      float v01 = (mi & 2) ? v1 : v0;
      float v23 = (mi & 2) ? v3 : v2;
      float v = (mi & 4) ? v23 : v01;
      v = v > 0.f ? v : (__expf(v) - 1.f);                     // elu
      outt[((size_t)(b*T_ + t)*N_ + (n0 + np))*C_ + lane] = v; // coalesced (b,t,n,c)
    }
  }
}

// ---------------- Kernel D: in-place (b,t,n,c) -> (b,c,n,t); t<->c are both 64 (involution)
__global__ __launch_bounds__(256) void k_tr(float* __restrict__ out){
  __shared__ float tile[64][65];
  int bid = blockIdx.x;
  int b = bid >> 8, n = bid & 255;
  int tid = threadIdx.x;
  float* base = out + (size_t)b*T_*N_*C_ + n*C_;   // element (x,y): base + x*N_*C_ + y
#pragma unroll
  for (int i = 0; i < 4; ++i){
    int chunk = tid + i*256;                       // 1024 float4 chunks
    int x = chunk >> 4, yc = (chunk & 15)*4;
    float4 v = *(const float4*)(base + (size_t)x*(N_*C_) + yc);
    tile[x][yc] = v.x; tile[x][yc+1] = v.y; tile[x][yc+2] = v.z; tile[x][yc+3] = v.w;
  }
  __syncthreads();
#pragma unroll
  for (int i = 0; i < 4; ++i){
    int chunk = tid + i*256;
    int x = chunk >> 4, yc = (chunk & 15)*4;
    float4 v;
    v.x = tile[yc  ][x];
    v.y = tile[yc+1][x];
    v.z = tile[yc+2][x];
    v.w = tile[yc+3][x];
    *(float4*)(base + (size_t)x*(N_*C_) + yc) = v;
  }
}

extern "C" void kernel_launch(void* const* d_in, const int* in_sizes, int n_in,
                              void* d_out, int out_size, void* d_ws, size_t ws_size,
                              hipStream_t stream){
  (void)in_sizes; (void)n_in; (void)out_size; (void)ws_size;
  const float* h   = (const float*)d_in[0];
  const int*   adj = (const int*)d_in[1];
  const float* W   = (const float*)d_in[2];
  const float* a   = (const float*)d_in[3];
  float* u    = (float*)d_ws;                       // 2*B*F f32
  float* fvec = u + 2*B_*F_;                        // B*N*T f32
  float* gvec = fvec + B_*N_*T_;                    // B*N*T f32
  unsigned short* wht = (unsigned short*)(gvec + B_*N_*T_);  // B*T*N*C bf16

  k_u   <<<dim3(B_),     dim3(F_), 0, stream>>>(W, a, u);
  k_wh  <<<dim3(B_*N_),  dim3(256), 0, stream>>>(h, W, u, wht, fvec, gvec);
  k_attn<<<dim3(B_*T_),  dim3(256), 0, stream>>>(wht, adj, fvec, gvec, (float*)d_out);
  k_tr  <<<dim3(B_*N_),  dim3(256), 0, stream>>>((float*)d_out);
}

// Round 2
// 192.016 us; speedup vs baseline: 2.6009x; 2.6009x over previous
//
#include <hip/hip_runtime.h>

#define B_ 16
#define F_ 128
#define N_ 256
#define T_ 64
#define C_ 64
#define NEG_INF_ -9000000000000000.0f
#define ALPHA_ 0.2f

typedef short bf16x8 __attribute__((ext_vector_type(8)));
typedef float f32x4 __attribute__((ext_vector_type(4)));

__device__ __forceinline__ unsigned short f2bf(float x){
  unsigned int u = __float_as_uint(x);
  unsigned int r = u + 0x7FFFu + ((u >> 16) & 1u);   // RNE
  return (unsigned short)(r >> 16);
}

// ---------------- Kernel A: u1[b][f] = sum_c W[b][f][c]*a1[b][c]; u2 with a2
__global__ void k_u(const float* __restrict__ W, const float* __restrict__ a,
                    float* __restrict__ u){
  int b = blockIdx.x, f = threadIdx.x;            // grid(B), block(F)
  const float* Wb = W + (b*F_ + f)*C_;
  const float* ab = a + b*2*C_;
  float s1 = 0.f, s2 = 0.f;
#pragma unroll 8
  for (int c = 0; c < C_; ++c){
    float w = Wb[c];
    s1 = fmaf(w, ab[c], s1);
    s2 = fmaf(w, ab[C_ + c], s2);
  }
  u[b*F_ + f] = s1;
  u[B_*F_ + b*F_ + f] = s2;
}

// ---------------- Kernel A2: adjacency row bitmasks, amask[b][n][8] u32
__global__ void k_mask(const int* __restrict__ adj, unsigned* __restrict__ amask){
  int blk = blockIdx.x;                 // grid B_*4
  int b = blk >> 2, r0 = (blk & 3)*64;
  int w = threadIdx.x >> 6, l = threadIdx.x & 63;
  const int* ab = adj + ((size_t)b*N_ + r0 + w*16)*N_;
  unsigned* om = amask + ((size_t)b*N_ + r0 + w*16)*8;
  for (int r = 0; r < 16; ++r){
    unsigned long long m0 = __ballot(ab[r*N_ +       l] > 0);
    unsigned long long m1 = __ballot(ab[r*N_ +  64 + l] > 0);
    unsigned long long m2 = __ballot(ab[r*N_ + 128 + l] > 0);
    unsigned long long m3 = __ballot(ab[r*N_ + 192 + l] > 0);
    if (l == 0){
      *(uint4*)(om + r*8)     = make_uint4((unsigned)m0, (unsigned)(m0>>32),
                                           (unsigned)m1, (unsigned)(m1>>32));
      *(uint4*)(om + r*8 + 4) = make_uint4((unsigned)m2, (unsigned)(m2>>32),
                                           (unsigned)m3, (unsigned)(m3>>32));
    }
  }
}

// ---------------- Kernel B: per (b,n): Wh_t[b][t][n][c] (bf16), and f,g (f32)
__global__ __launch_bounds__(256) void k_wh(const float* __restrict__ h,
    const float* __restrict__ W, const float* __restrict__ u,
    unsigned short* __restrict__ wht, float* __restrict__ fvec,
    float* __restrict__ gvec){
  __shared__ float hs[F_][T_];   // 32KB  (f x t)
  __shared__ float Ws[F_][C_];   // 32KB  (f x c)
  int bid = blockIdx.x;
  int b = bid >> 8, n = bid & 255;
  int tid = threadIdx.x;
  const float* hb = h + (size_t)b*F_*N_*T_ + n*T_;
#pragma unroll
  for (int i = 0; i < 8; ++i){
    int chunk = tid + i*256;                 // 2048 float4 chunks
    int f = chunk >> 4, tc = (chunk & 15)*4;
    *(float4*)&hs[f][tc] = *(const float4*)(hb + (size_t)f*(N_*T_) + tc);
  }
  const float* Wb = W + b*(F_*C_);
#pragma unroll
  for (int i = 0; i < 8; ++i){
    int chunk = tid + i*256;
    *(float4*)(&Ws[0][0] + chunk*4) = *(const float4*)(Wb + chunk*4);
  }
  __syncthreads();

  int c0 = (tid & 15)*4, t0 = (tid >> 4)*4;
  float acc[4][4] = {};
#pragma unroll 2
  for (int f = 0; f < F_; ++f){
    float wv[4], hv[4];
    *(float4*)wv = *(const float4*)&Ws[f][c0];
    *(float4*)hv = *(const float4*)&hs[f][t0];
#pragma unroll
    for (int i = 0; i < 4; ++i)
#pragma unroll
      for (int j = 0; j < 4; ++j)
        acc[i][j] = fmaf(wv[i], hv[j], acc[i][j]);
  }

  // f,g in full f32 (precision-critical for the sharp softmax logits)
  if (tid < T_){
    const float* u1 = u + b*F_;
    const float* u2 = u + B_*F_ + b*F_;
    float sf = 0.f, sg = 0.f;
#pragma unroll 4
    for (int f = 0; f < F_; ++f){
      float hv = hs[f][tid];
      sf = fmaf(hv, u1[f], sf);
      sg = fmaf(hv, u2[f], sg);
    }
    fvec[(b*N_ + n)*T_ + tid] = sf;
    gvec[(b*N_ + n)*T_ + tid] = sg;
  }

  // store Wh_t[b][t][n][c] as bf16, coalesced over c
#pragma unroll
  for (int j = 0; j < 4; ++j){
    unsigned int p0 = ((unsigned int)f2bf(acc[1][j]) << 16) | f2bf(acc[0][j]);
    unsigned int p1 = ((unsigned int)f2bf(acc[3][j]) << 16) | f2bf(acc[2][j]);
    size_t idx = ((size_t)(b*T_ + t0 + j)*N_ + n)*C_ + c0;
    *(uint2*)(wht + idx) = make_uint2(p0, p1);
  }
}

// ---------------- Kernel C: per (b,t): row-per-lane softmax + MFMA PV
// writes (b,t,n,c) f32 into d_out
__global__ __launch_bounds__(256, 3) void k_attn(
    const unsigned short* __restrict__ wht,   // [b][t][n][c] bf16
    const unsigned* __restrict__ amask,       // [b][n][8]
    const float* __restrict__ fvec, const float* __restrict__ gvec,
    float* __restrict__ outt){
  __shared__ uint4 whsT4[2048];   // 32KB: Wh^T [c][m] bf16, XOR-swizzled
  __shared__ uint4 alds4[1024];   // 16KB: per-wave attn chunk [64 rows][32 m] bf16, swizzled
  __shared__ float gs[N_];
  __shared__ float invs[N_];
  char* dstT = (char*)whsT4;
  char* aldsb = (char*)alds4;

  int bid = blockIdx.x;
  int b = bid >> 6, t = bid & 63;
  int tid = threadIdx.x, w = tid >> 6, l = tid & 63;
  // lane owns row n = tid

  gs[tid] = gvec[(b*N_ + tid)*T_ + t];
  float fl = fvec[(b*N_ + tid)*T_ + t];
  const unsigned* gmask = amask + ((size_t)b*N_ + tid)*8;
  const uint4* mq = (const uint4*)gmask;
  uint4 mwA = mq[0], mwB = mq[1];

  // ---- stage Wh^T[c][m] (2x2 pair transpose via v_perm), swizzle bits 4..6
  const char* src = (const char*)(wht + (size_t)(b*T_ + t)*(N_*C_));
#pragma unroll
  for (int i = 0; i < 4; ++i){
    int q2 = tid + i*256;                  // 1024 2-row x 8-col tiles
    int m = (q2 >> 3)*2, c0 = (q2 & 7)*8;
    uint4 ra = *(const uint4*)(src + m*128 + c0*2);
    uint4 rb = *(const uint4*)(src + (m+1)*128 + c0*2);
    unsigned va[4] = {ra.x, ra.y, ra.z, ra.w};
    unsigned vb[4] = {rb.x, rb.y, rb.z, rb.w};
#pragma unroll
    for (int k = 0; k < 4; ++k){
      int c = c0 + 2*k;
      unsigned lo = __builtin_amdgcn_perm(vb[k], va[k], 0x05040100u); // (m+1|m) @ col c
      unsigned hi = __builtin_amdgcn_perm(vb[k], va[k], 0x07060302u); // (m+1|m) @ col c+1
      *(unsigned*)(dstT + ((( c   *512) + m*2) ^ (((c  ) & 7) << 4))) = lo;
      *(unsigned*)(dstT + ((((c+1)*512) + m*2) ^ (((c+1) & 7) << 4))) = hi;
    }
  }
  __syncthreads();

  // ---- pass 1: masked max of g over m (lrelu monotone => emax = lrelu(f + maxg))
  float mg = -1e5f;
  {
    unsigned mw[8] = {mwA.x, mwA.y, mwA.z, mwA.w, mwB.x, mwB.y, mwB.z, mwB.w};
#pragma unroll
    for (int i = 0; i < 8; ++i){
      unsigned wd = mw[i];
#pragma unroll
      for (int j4 = 0; j4 < 8; ++j4){
        float4 g4 = *(const float4*)&gs[i*32 + j4*4];
        float s0 = ((wd >> (j4*4+0)) & 1u) ? g4.x : -1e5f;
        float s1 = ((wd >> (j4*4+1)) & 1u) ? g4.y : -1e5f;
        float s2 = ((wd >> (j4*4+2)) & 1u) ? g4.z : -1e5f;
        float s3 = ((wd >> (j4*4+3)) & 1u) ? g4.w : -1e5f;
        mg = fmaxf(mg, fmaxf(fmaxf(s0, s1), fmaxf(s2, s3)));
      }
    }
  }
  float me = fl + mg;
  me = fmaxf(me, ALPHA_*me);

  // ---- pass 2: per-chunk unnormalized weights -> LDS -> MFMA PV
  f32x4 acc[4][4];
#pragma unroll
  for (int mt = 0; mt < 4; ++mt)
#pragma unroll
    for (int nt = 0; nt < 4; ++nt)
      acc[mt][nt] = (f32x4){0.f, 0.f, 0.f, 0.f};
  float sum = 0.f;
  char* aw = aldsb + w*4096;
  int g_ = l >> 4, li = l & 15;

#pragma unroll 1
  for (int ch = 0; ch < 8; ++ch){
    unsigned wd = gmask[ch];               // reload (L1/L2-hot) -> no runtime reg indexing
#pragma unroll
    for (int part = 0; part < 4; ++part){
      float4 ga = *(const float4*)&gs[ch*32 + part*8];
      float4 gb = *(const float4*)&gs[ch*32 + part*8 + 4];
      float gg[8] = {ga.x, ga.y, ga.z, ga.w, gb.x, gb.y, gb.z, gb.w};
      float wv[8];
#pragma unroll
      for (int jj = 0; jj < 8; ++jj){
        float e  = fl + gg[jj];
        float lr = fmaxf(e, ALPHA_*e);
        float x  = fminf(lr - me, 0.f);    // exact for adjacent; kills inf*0 for masked
        float p  = __expf(x);
        float bitf = (float)((wd >> (part*8 + jj)) & 1u);
        float v  = p * bitf;
        sum += v;
        wv[jj] = v;
      }
      unsigned q0 = (__float_as_uint(wv[1]) & 0xFFFF0000u) | (__float_as_uint(wv[0]) >> 16);
      unsigned q1 = (__float_as_uint(wv[3]) & 0xFFFF0000u) | (__float_as_uint(wv[2]) >> 16);
      unsigned q2 = (__float_as_uint(wv[5]) & 0xFFFF0000u) | (__float_as_uint(wv[4]) >> 16);
      unsigned q3 = (__float_as_uint(wv[7]) & 0xFFFF0000u) | (__float_as_uint(wv[6]) >> 16);
      *(uint4*)(aw + ((l*64 + part*16) ^ ((l & 7) << 4))) = make_uint4(q0, q1, q2, q3);
    }
    // B fragments: Wh^T rows c, 8 consecutive m
    bf16x8 bfr[4];
#pragma unroll
    for (int nt = 0; nt < 4; ++nt){
      int c = nt*16 + li;
      bfr[nt] = *(bf16x8*)(dstT + ((c*512 + (ch*32 + g_*8)*2) ^ ((c & 7) << 4)));
    }
#pragma unroll
    for (int mt = 0; mt < 4; ++mt){
      int r = mt*16 + li;
      bf16x8 af = *(bf16x8*)(aw + ((r*64 + g_*16) ^ ((r & 7) << 4)));
#pragma unroll
      for (int nt = 0; nt < 4; ++nt)
        acc[mt][nt] = __builtin_amdgcn_mfma_f32_16x16x32_bf16(af, bfr[nt], acc[mt][nt], 0, 0, 0);
    }
  }

  invs[tid] = 1.0f / sum;
  // within-wave LDS read of other lanes' invs: no barrier needed
  float* outp = outt + ((size_t)(b*T_ + t)*N_ + (size_t)w*64)*C_;
#pragma unroll
  for (int mt = 0; mt < 4; ++mt){
#pragma unroll
    for (int reg = 0; reg < 4; ++reg){
      int row = mt*16 + g_*4 + reg;
      float inv = invs[w*64 + row];
#pragma unroll
      for (int nt = 0; nt < 4; ++nt){
        float v = acc[mt][nt][reg] * inv;
        v = v > 0.f ? v : (__expf(v) - 1.f);              // elu
        outp[row*C_ + nt*16 + li] = v;
      }
    }
  }
}

// ---------------- Kernel D: in-place (b,t,n,c) -> (b,c,n,t); t<->c are both 64 (involution)
__global__ __launch_bounds__(256) void k_tr(float* __restrict__ out){
  __shared__ float tile[64][65];
  int bid = blockIdx.x;
  int b = bid >> 8, n = bid & 255;
  int tid = threadIdx.x;
  float* base = out + (size_t)b*T_*N_*C_ + n*C_;   // element (x,y): base + x*N_*C_ + y
#pragma unroll
  for (int i = 0; i < 4; ++i){
    int chunk = tid + i*256;                       // 1024 float4 chunks
    int x = chunk >> 4, yc = (chunk & 15)*4;
    float4 v = *(const float4*)(base + (size_t)x*(N_*C_) + yc);
    tile[x][yc] = v.x; tile[x][yc+1] = v.y; tile[x][yc+2] = v.z; tile[x][yc+3] = v.w;
  }
  __syncthreads();
#pragma unroll
  for (int i = 0; i < 4; ++i){
    int chunk = tid + i*256;
    int x = chunk >> 4, yc = (chunk & 15)*4;
    float4 v;
    v.x = tile[yc  ][x];
    v.y = tile[yc+1][x];
    v.z = tile[yc+2][x];
    v.w = tile[yc+3][x];
    *(float4*)(base + (size_t)x*(N_*C_) + yc) = v;
  }
}

extern "C" void kernel_launch(void* const* d_in, const int* in_sizes, int n_in,
                              void* d_out, int out_size, void* d_ws, size_t ws_size,
                              hipStream_t stream){
  (void)in_sizes; (void)n_in; (void)out_size; (void)ws_size;
  const float* h   = (const float*)d_in[0];
  const int*   adj = (const int*)d_in[1];
  const float* W   = (const float*)d_in[2];
  const float* a   = (const float*)d_in[3];
  float* u    = (float*)d_ws;                       // 2*B*F f32
  float* fvec = u + 2*B_*F_;                        // B*N*T f32
  float* gvec = fvec + B_*N_*T_;                    // B*N*T f32
  unsigned short* wht = (unsigned short*)(gvec + B_*N_*T_);  // B*T*N*C bf16
  unsigned* amask = (unsigned*)(wht + (size_t)B_*T_*N_*C_);  // B*N*8 u32

  k_u   <<<dim3(B_),      dim3(F_),  0, stream>>>(W, a, u);
  k_mask<<<dim3(B_*4),    dim3(256), 0, stream>>>(adj, amask);
  k_wh  <<<dim3(B_*N_),   dim3(256), 0, stream>>>(h, W, u, wht, fvec, gvec);
  k_attn<<<dim3(B_*T_),   dim3(256), 0, stream>>>(wht, amask, fvec, gvec, (float*)d_out);
  k_tr  <<<dim3(B_*N_),   dim3(256), 0, stream>>>((float*)d_out);
}

// Round 3
// 113.752 us; speedup vs baseline: 4.3905x; 1.6880x over previous
//
#include <hip/hip_runtime.h>

#define B_ 16
#define F_ 128
#define N_ 256
#define T_ 64
#define C_ 64
#define NEG_INF_ -9000000000000000.0f
#define ALPHA_ 0.2f

typedef short bf16x8 __attribute__((ext_vector_type(8)));
typedef float f32x4 __attribute__((ext_vector_type(4)));

__device__ __forceinline__ unsigned short f2bf(float x){
  unsigned int u = __float_as_uint(x);
  unsigned int r = u + 0x7FFFu + ((u >> 16) & 1u);   // RNE
  return (unsigned short)(r >> 16);
}
__device__ __forceinline__ unsigned pk2(float a, float b){
  return ((unsigned)f2bf(b) << 16) | (unsigned)f2bf(a);
}

// ---------------- Kernel A: u1[b][f] = sum_c W[b][f][c]*a1[b][c]; u2 with a2
__global__ void k_u(const float* __restrict__ W, const float* __restrict__ a,
                    float* __restrict__ u){
  int b = blockIdx.x, f = threadIdx.x;            // grid(B), block(F)
  const float* Wb = W + (b*F_ + f)*C_;
  const float* ab = a + b*2*C_;
  float s1 = 0.f, s2 = 0.f;
#pragma unroll 8
  for (int c = 0; c < C_; ++c){
    float w = Wb[c];
    s1 = fmaf(w, ab[c], s1);
    s2 = fmaf(w, ab[C_ + c], s2);
  }
  u[b*F_ + f] = s1;
  u[B_*F_ + b*F_ + f] = s2;
}

// ---------------- Kernel A2: adjacency row bitmasks, amask[b][n][8] u32
__global__ void k_mask(const int* __restrict__ adj, unsigned* __restrict__ amask){
  int blk = blockIdx.x;                 // grid B_*4
  int b = blk >> 2, r0 = (blk & 3)*64;
  int w = threadIdx.x >> 6, l = threadIdx.x & 63;
  const int* ab = adj + ((size_t)b*N_ + r0 + w*16)*N_;
  unsigned* om = amask + ((size_t)b*N_ + r0 + w*16)*8;
  for (int r = 0; r < 16; ++r){
    unsigned long long m0 = __ballot(ab[r*N_ +       l] > 0);
    unsigned long long m1 = __ballot(ab[r*N_ +  64 + l] > 0);
    unsigned long long m2 = __ballot(ab[r*N_ + 128 + l] > 0);
    unsigned long long m3 = __ballot(ab[r*N_ + 192 + l] > 0);
    if (l == 0){
      *(uint4*)(om + r*8)     = make_uint4((unsigned)m0, (unsigned)(m0>>32),
                                           (unsigned)m1, (unsigned)(m1>>32));
      *(uint4*)(om + r*8 + 4) = make_uint4((unsigned)m2, (unsigned)(m2>>32),
                                           (unsigned)m3, (unsigned)(m3>>32));
    }
  }
}

// ---------------- Kernel B: per (b,n): Wh_t[b][t][n][c] (bf16) via MFMA; f,g f32
__global__ __launch_bounds__(256, 4) void k_wh(const float* __restrict__ h,
    const float* __restrict__ W, const float* __restrict__ u,
    unsigned short* __restrict__ wht, float* __restrict__ fvec,
    float* __restrict__ gvec){
  __shared__ uint4 hT4[1024];    // 16KB: hT[t][f] bf16, 256B rows, XOR swz bits4-6
  __shared__ uint4 wT4[1024];    // 16KB: wT[c][f] bf16, same layout
  __shared__ float fpart[4][T_];
  __shared__ float gpart[4][T_];
  char* hT = (char*)hT4;
  char* wT = (char*)wT4;

  int bid = blockIdx.x, b = bid >> 8, n = bid & 255;
  int tid = threadIdx.x, w = tid >> 6, l = tid & 63;
  const float* hg = h + (size_t)b*F_*N_*T_ + n*T_;
  const float* Wg = W + b*F_*C_;
  const float* u1 = u + b*F_;
  const float* u2 = u + B_*F_ + b*F_;

  float sf = 0.f, sg = 0.f;
#pragma unroll
  for (int p = 0; p < 4; ++p){
    int f0 = p*32 + w*8;
    float v[8], wv[8];
#pragma unroll
    for (int j = 0; j < 8; ++j){
      v[j]  = hg[(size_t)(f0+j)*(N_*T_) + l];      // coalesced 256B per wave
      wv[j] = Wg[(f0+j)*C_ + l];                   // coalesced 256B per wave
      sf = fmaf(v[j], u1[f0+j], sf);               // f32 f/g (precision-critical)
      sg = fmaf(v[j], u2[f0+j], sg);
    }
    uint4 ph = make_uint4(pk2(v[0],v[1]),  pk2(v[2],v[3]),  pk2(v[4],v[5]),  pk2(v[6],v[7]));
    uint4 pw = make_uint4(pk2(wv[0],wv[1]),pk2(wv[2],wv[3]),pk2(wv[4],wv[5]),pk2(wv[6],wv[7]));
    *(uint4*)(hT + ((l*256 + f0*2) ^ ((l & 7) << 4))) = ph;   // hT[t=l][f0..f0+7]
    *(uint4*)(wT + ((l*256 + f0*2) ^ ((l & 7) << 4))) = pw;   // wT[c=l][f0..f0+7]
  }
  fpart[w][l] = sf;
  gpart[w][l] = sg;
  __syncthreads();

  if (tid < T_){
    float f_ = (fpart[0][tid] + fpart[1][tid]) + (fpart[2][tid] + fpart[3][tid]);
    float g_ = (gpart[0][tid] + gpart[1][tid]) + (gpart[2][tid] + gpart[3][tid]);
    fvec[(b*N_ + n)*T_ + tid] = f_;
    gvec[(b*N_ + n)*T_ + tid] = g_;
  }

  // MFMA: D[c][t], wave w owns c rows [w*16, w*16+16)
  int li = l & 15, g_ = l >> 4;
  bf16x8 afr[4];
#pragma unroll
  for (int ch = 0; ch < 4; ++ch){
    int c = w*16 + li;
    afr[ch] = *(bf16x8*)(wT + ((c*256 + (ch*32 + g_*8)*2) ^ ((c & 7) << 4)));
  }
  f32x4 acc[4];
#pragma unroll
  for (int tt = 0; tt < 4; ++tt) acc[tt] = (f32x4){0.f,0.f,0.f,0.f};
#pragma unroll
  for (int tt = 0; tt < 4; ++tt){
#pragma unroll
    for (int ch = 0; ch < 4; ++ch){
      int t = tt*16 + li;
      bf16x8 bfr = *(bf16x8*)(hT + ((t*256 + (ch*32 + g_*8)*2) ^ ((t & 7) << 4)));
      acc[tt] = __builtin_amdgcn_mfma_f32_16x16x32_bf16(afr[ch], bfr, acc[tt], 0, 0, 0);
    }
  }
  // store: lane holds t = tt*16+li (col), c = w*16 + g_*4 + reg (row)
  unsigned short* wb = wht + ((size_t)b*T_*N_ + n)*C_;
#pragma unroll
  for (int tt = 0; tt < 4; ++tt){
    int t = tt*16 + li;
    int c0 = w*16 + g_*4;
    unsigned q0 = pk2(acc[tt][0], acc[tt][1]);
    unsigned q1 = pk2(acc[tt][2], acc[tt][3]);
    *(uint2*)(wb + (size_t)t*(N_*C_) + c0) = make_uint2(q0, q1);
  }
}

// ---------------- Kernel C: per (b,t): row-per-lane softmax + MFMA PV
// overwrites its own block-private wht slab with bf16 (t,n,c) output
__global__ __launch_bounds__(256, 3) void k_attn(
    unsigned short* wht,                      // [b][t][n][c] bf16 (in AND out)
    const unsigned* __restrict__ amask,       // [b][n][8]
    const float* __restrict__ fvec, const float* __restrict__ gvec){
  __shared__ uint4 whsT4[2048];   // 32KB: Wh^T [c][m] bf16, XOR-swizzled
  __shared__ uint4 alds4[1024];   // 16KB: per-wave attn chunk [64 rows][32 m] bf16, swizzled
  __shared__ float gs[N_];
  __shared__ float invs[N_];
  char* dstT = (char*)whsT4;
  char* aldsb = (char*)alds4;

  int bid = blockIdx.x;
  int b = bid >> 6, t = bid & 63;
  int tid = threadIdx.x, w = tid >> 6, l = tid & 63;
  // lane owns row n = tid

  gs[tid] = gvec[(b*N_ + tid)*T_ + t];
  float fl = fvec[(b*N_ + tid)*T_ + t];
  const unsigned* gmask = amask + ((size_t)b*N_ + tid)*8;
  const uint4* mq = (const uint4*)gmask;
  uint4 mwA = mq[0], mwB = mq[1];

  // ---- stage Wh^T[c][m] (2x2 pair transpose via v_perm), swizzle bits 4..6
  const char* src = (const char*)(wht + (size_t)(b*T_ + t)*(N_*C_));
#pragma unroll
  for (int i = 0; i < 4; ++i){
    int q2 = tid + i*256;                  // 1024 2-row x 8-col tiles
    int m = (q2 >> 3)*2, c0 = (q2 & 7)*8;
    uint4 ra = *(const uint4*)(src + m*128 + c0*2);
    uint4 rb = *(const uint4*)(src + (m+1)*128 + c0*2);
    unsigned va[4] = {ra.x, ra.y, ra.z, ra.w};
    unsigned vb[4] = {rb.x, rb.y, rb.z, rb.w};
#pragma unroll
    for (int k = 0; k < 4; ++k){
      int c = c0 + 2*k;
      unsigned lo = __builtin_amdgcn_perm(vb[k], va[k], 0x05040100u); // (m+1|m) @ col c
      unsigned hi = __builtin_amdgcn_perm(vb[k], va[k], 0x07060302u); // (m+1|m) @ col c+1
      *(unsigned*)(dstT + ((( c   *512) + m*2) ^ (((c  ) & 7) << 4))) = lo;
      *(unsigned*)(dstT + ((((c+1)*512) + m*2) ^ (((c+1) & 7) << 4))) = hi;
    }
  }
  __syncthreads();

  // ---- pass 1: masked max of g over m (lrelu monotone => emax = lrelu(f + maxg))
  float mg = -1e5f;
  {
    unsigned mw[8] = {mwA.x, mwA.y, mwA.z, mwA.w, mwB.x, mwB.y, mwB.z, mwB.w};
#pragma unroll
    for (int i = 0; i < 8; ++i){
      unsigned wd = mw[i];
#pragma unroll
      for (int j4 = 0; j4 < 8; ++j4){
        float4 g4 = *(const float4*)&gs[i*32 + j4*4];
        float s0 = ((wd >> (j4*4+0)) & 1u) ? g4.x : -1e5f;
        float s1 = ((wd >> (j4*4+1)) & 1u) ? g4.y : -1e5f;
        float s2 = ((wd >> (j4*4+2)) & 1u) ? g4.z : -1e5f;
        float s3 = ((wd >> (j4*4+3)) & 1u) ? g4.w : -1e5f;
        mg = fmaxf(mg, fmaxf(fmaxf(s0, s1), fmaxf(s2, s3)));
      }
    }
  }
  float me = fl + mg;
  me = fmaxf(me, ALPHA_*me);

  // ---- pass 2: per-chunk unnormalized weights -> LDS -> MFMA PV
  f32x4 acc[4][4];
#pragma unroll
  for (int mt = 0; mt < 4; ++mt)
#pragma unroll
    for (int nt = 0; nt < 4; ++nt)
      acc[mt][nt] = (f32x4){0.f, 0.f, 0.f, 0.f};
  float sum = 0.f;
  char* aw = aldsb + w*4096;
  int g_ = l >> 4, li = l & 15;

#pragma unroll 1
  for (int ch = 0; ch < 8; ++ch){
    unsigned wd = gmask[ch];               // reload (L1/L2-hot) -> no runtime reg indexing
#pragma unroll
    for (int part = 0; part < 4; ++part){
      float4 ga = *(const float4*)&gs[ch*32 + part*8];
      float4 gb = *(const float4*)&gs[ch*32 + part*8 + 4];
      float gg[8] = {ga.x, ga.y, ga.z, ga.w, gb.x, gb.y, gb.z, gb.w};
      float wv[8];
#pragma unroll
      for (int jj = 0; jj < 8; ++jj){
        float e  = fl + gg[jj];
        float lr = fmaxf(e, ALPHA_*e);
        float x  = fminf(lr - me, 0.f);    // exact for adjacent; kills inf*0 for masked
        float p  = __expf(x);
        float bitf = (float)((wd >> (part*8 + jj)) & 1u);
        float v  = p * bitf;
        sum += v;
        wv[jj] = v;
      }
      unsigned q0 = (__float_as_uint(wv[1]) & 0xFFFF0000u) | (__float_as_uint(wv[0]) >> 16);
      unsigned q1 = (__float_as_uint(wv[3]) & 0xFFFF0000u) | (__float_as_uint(wv[2]) >> 16);
      unsigned q2 = (__float_as_uint(wv[5]) & 0xFFFF0000u) | (__float_as_uint(wv[4]) >> 16);
      unsigned q3 = (__float_as_uint(wv[7]) & 0xFFFF0000u) | (__float_as_uint(wv[6]) >> 16);
      *(uint4*)(aw + ((l*64 + part*16) ^ ((l & 7) << 4))) = make_uint4(q0, q1, q2, q3);
    }
    // B fragments: Wh^T rows c, 8 consecutive m
    bf16x8 bfr[4];
#pragma unroll
    for (int nt = 0; nt < 4; ++nt){
      int c = nt*16 + li;
      bfr[nt] = *(bf16x8*)(dstT + ((c*512 + (ch*32 + g_*8)*2) ^ ((c & 7) << 4)));
    }
#pragma unroll
    for (int mt = 0; mt < 4; ++mt){
      int r = mt*16 + li;
      bf16x8 af = *(bf16x8*)(aw + ((r*64 + g_*16) ^ ((r & 7) << 4)));
#pragma unroll
      for (int nt = 0; nt < 4; ++nt)
        acc[mt][nt] = __builtin_amdgcn_mfma_f32_16x16x32_bf16(af, bfr[nt], acc[mt][nt], 0, 0, 0);
    }
  }

  invs[tid] = 1.0f / sum;
  // within-wave LDS read of other lanes' invs: no barrier needed
  unsigned short* ob = wht + (size_t)(b*T_ + t)*(N_*C_) + (size_t)w*64*C_;
#pragma unroll
  for (int mt = 0; mt < 4; ++mt){
#pragma unroll
    for (int reg = 0; reg < 4; ++reg){
      int row = mt*16 + g_*4 + reg;
      float inv = invs[w*64 + row];
#pragma unroll
      for (int nt = 0; nt < 4; ++nt){
        float v = acc[mt][nt][reg] * inv;
        v = v > 0.f ? v : (__expf(v) - 1.f);              // elu
        ob[row*C_ + nt*16 + li] = f2bf(v);                // bf16 (t,n,c) into own slab
      }
    }
  }
}

// ---------------- Kernel D: (b,t,n,c) bf16 -> (b,c,n,t) f32
__global__ __launch_bounds__(256) void k_tr(const unsigned short* __restrict__ whtO,
                                            float* __restrict__ out){
  __shared__ float tile[64][65];
  int bid = blockIdx.x;
  int b = bid >> 8, n = bid & 255;
  int tid = threadIdx.x;
  const unsigned short* src = whtO + ((size_t)b*T_*N_ + n)*C_;   // + t*N*C + c
#pragma unroll
  for (int i = 0; i < 2; ++i){
    int idx = tid + i*256;                 // 512 uint4 chunks: 64 t-rows x 8
    int t = idx >> 3, c0 = (idx & 7)*8;
    uint4 v = *(const uint4*)(src + (size_t)t*(N_*C_) + c0);
    unsigned arr[4] = {v.x, v.y, v.z, v.w};
#pragma unroll
    for (int k = 0; k < 4; ++k){
      tile[c0+2*k  ][t] = __uint_as_float(arr[k] << 16);
      tile[c0+2*k+1][t] = __uint_as_float(arr[k] & 0xFFFF0000u);
    }
  }
  __syncthreads();
  float* ob = out + (size_t)b*C_*N_*T_ + n*T_;                   // + c*N*T + t
#pragma unroll
  for (int i = 0; i < 4; ++i){
    int idx = tid + i*256;                 // 1024 float4: 64 c-rows x 16
    int c = idx >> 4, t0 = (idx & 15)*4;
    float4 v = make_float4(tile[c][t0], tile[c][t0+1], tile[c][t0+2], tile[c][t0+3]);
    *(float4*)(ob + (size_t)c*(N_*T_) + t0) = v;
  }
}

extern "C" void kernel_launch(void* const* d_in, const int* in_sizes, int n_in,
                              void* d_out, int out_size, void* d_ws, size_t ws_size,
                              hipStream_t stream){
  (void)in_sizes; (void)n_in; (void)out_size; (void)ws_size;
  const float* h   = (const float*)d_in[0];
  const int*   adj = (const int*)d_in[1];
  const float* W   = (const float*)d_in[2];
  const float* a   = (const float*)d_in[3];
  float* u    = (float*)d_ws;                       // 2*B*F f32
  float* fvec = u + 2*B_*F_;                        // B*N*T f32
  float* gvec = fvec + B_*N_*T_;                    // B*N*T f32
  unsigned short* wht = (unsigned short*)(gvec + B_*N_*T_);  // B*T*N*C bf16
  unsigned* amask = (unsigned*)(wht + (size_t)B_*T_*N_*C_);  // B*N*8 u32

  k_u   <<<dim3(B_),      dim3(F_),  0, stream>>>(W, a, u);
  k_mask<<<dim3(B_*4),    dim3(256), 0, stream>>>(adj, amask);
  k_wh  <<<dim3(B_*N_),   dim3(256), 0, stream>>>(h, W, u, wht, fvec, gvec);
  k_attn<<<dim3(B_*T_),   dim3(256), 0, stream>>>(wht, amask, fvec, gvec);
  k_tr  <<<dim3(B_*N_),   dim3(256), 0, stream>>>(wht, (float*)d_out);
}